// Round 7
// baseline (363.329 us; speedup 1.0000x reference)
//
#include <hip/hip_runtime.h>
#include <hip/hip_bf16.h>

#define IN_DIM  128
#define HID_DIM 128
#define OUT_DIM 64
#define NREP    8          // counter replicas (contention /8)
#define G1B     1024       // gemm1 persistent blocks inside fused kernel

typedef unsigned short ushort_t;
struct ushort4_t { ushort_t x, y, z, w; };
typedef __attribute__((ext_vector_type(8))) short bf16x8;   // 8 bf16 (4 VGPRs)
typedef __attribute__((ext_vector_type(4))) float f32x4;    // MFMA acc

__device__ __forceinline__ float bf2f(ushort_t u) {
    return __uint_as_float(((unsigned int)u) << 16);
}
__device__ __forceinline__ short f2bf_s(float v) {
    __hip_bfloat16 t = __float2bfloat16(v);
    return *(short*)&t;
}
__device__ __forceinline__ unsigned int pack2(float a, float b) {
    return ((unsigned int)(ushort_t)f2bf_s(b) << 16) | (ushort_t)f2bf_s(a);
}

// ---------------- replicated degree count + per-edge rank ----------------
__global__ void count_rank(const int* __restrict__ dst, int E, int N,
                           int* __restrict__ cntR, int* __restrict__ rank) {
    int e = blockIdx.x * blockDim.x + threadIdx.x;
    if (e < E) {
        int r = (e >> 8) & (NREP - 1);
        rank[e] = atomicAdd(&cntR[(size_t)r * N + dst[e]], 1);
    }
}

// ---------------- per-node totals: replica prefix (in place), dinv, padded cnt,
// ---------------- and per-block sums (merged scan_partial) ----------------
__global__ void node_totals(int* __restrict__ cntR, float* __restrict__ dinv,
                            int* __restrict__ cntp, int* __restrict__ bsum, int N) {
    __shared__ int wsum[4];
    const int t = threadIdx.x;
    const int base = blockIdx.x * 2048 + t * 8;
    int ssum = 0;
    #pragma unroll
    for (int i = 0; i < 8; ++i) {
        const int idx = base + i;
        if (idx < N) {
            int b = 0;
            #pragma unroll
            for (int r = 0; r < NREP; ++r) {
                int c = cntR[(size_t)r * N + idx];
                cntR[(size_t)r * N + idx] = b;   // exclusive base for fill
                b += c;
            }
            dinv[idx] = rsqrtf((float)(b + 1));  // +1 self loop
            int p = (b + 3) & ~3;
            cntp[idx] = p;
            ssum += p;
        }
    }
    #pragma unroll
    for (int off = 32; off > 0; off >>= 1) ssum += __shfl_down(ssum, off);
    const int lane = t & 63, w = t >> 6;
    if (lane == 0) wsum[w] = ssum;
    __syncthreads();
    if (t == 0) bsum[blockIdx.x] = wsum[0] + wsum[1] + wsum[2] + wsum[3];
}

__global__ void scan_partials(int* __restrict__ bsum, int S) {
    const int t = threadIdx.x;  // 64 threads, single wave
    int running = 0;
    for (int base = 0; base < S; base += 64) {
        int i = base + t;
        int v = (i < S) ? bsum[i] : 0;
        int incl = v;
        #pragma unroll
        for (int off = 1; off < 64; off <<= 1) {
            int u = __shfl_up(incl, off);
            if (t >= off) incl += u;
        }
        if (i < S) bsum[i] = running + incl - v;   // exclusive
        running += __shfl(incl, 63);
    }
}

__global__ void scan_write(const int* __restrict__ cntp, const int* __restrict__ bsum,
                           int* __restrict__ row_start, int N) {
    __shared__ int wsum[4];
    const int t = threadIdx.x;
    const int base = blockIdx.x * 2048 + t * 8;
    int v[8];
    #pragma unroll
    for (int i = 0; i < 8; ++i) v[i] = (base + i < N) ? cntp[base + i] : 0;
    int s = v[0] + v[1] + v[2] + v[3] + v[4] + v[5] + v[6] + v[7];
    const int lane = t & 63, w = t >> 6;
    int incl = s;
    #pragma unroll
    for (int off = 1; off < 64; off <<= 1) {
        int u = __shfl_up(incl, off);
        if (lane >= off) incl += u;
    }
    if (lane == 63) wsum[w] = incl;
    __syncthreads();
    int woff = 0;
    for (int i = 0; i < w; ++i) woff += wsum[i];
    int run = bsum[blockIdx.x] + woff + (incl - s);
    #pragma unroll
    for (int i = 0; i < 8; ++i) {
        if (base + i < N) row_start[base + i] = run;
        run += v[i];
    }
}

// ---------------- fused: gemm1 (MFMA, blocks < G1B) + fill_pack (blocks >= G1B) ----
// gemm1: h1[N,128](bf16) = x[N,128] @ W1[128,128], D = W1^T·x^T per 16-node tile.
// fill:  pack[row_start[d] + base[r][d] + rank[e]] = {src, dinv[s]*dinv[d]}.
__global__ __launch_bounds__(256, 2) void fused_fill_gemm1(
        const int* __restrict__ src, const int* __restrict__ dst,
        const int* __restrict__ rank, const int* __restrict__ row_start,
        const int* __restrict__ cntR, const float* __restrict__ dinv,
        int2* __restrict__ pack, int E,
        const float* __restrict__ x, const float* __restrict__ W,
        unsigned int* __restrict__ h, int N, int NT) {
    const int tid = threadIdx.x;
    if (blockIdx.x < G1B) {
        // ---- gemm1 role ----
        const int lane = tid & 63;
        const int m    = lane & 15;
        const int quad = lane >> 4;
        const int gw   = blockIdx.x * 4 + (tid >> 6);
        const int NW   = G1B * 4;

        bf16x8 a[8][4];                     // 8 col-tiles x 4 k-chunks
        #pragma unroll
        for (int ct = 0; ct < 8; ++ct)
            #pragma unroll
            for (int kc = 0; kc < 4; ++kc)
                #pragma unroll
                for (int j = 0; j < 8; ++j)
                    a[ct][kc][j] = f2bf_s(W[(size_t)(kc * 32 + quad * 8 + j) * HID_DIM + ct * 16 + m]);

        for (int t = gw; t < NT; t += NW) {
            const int n0 = t * 16;
            int node = n0 + m; if (node >= N) node = N - 1;
            const float* xr = x + (size_t)node * IN_DIM + quad * 8;
            f32x4 acc[8];
            #pragma unroll
            for (int ct = 0; ct < 8; ++ct) acc[ct] = (f32x4){0.f, 0.f, 0.f, 0.f};
            #pragma unroll
            for (int kc = 0; kc < 4; ++kc) {
                const float4 v0 = *(const float4*)(xr + kc * 32);
                const float4 v1 = *(const float4*)(xr + kc * 32 + 4);
                bf16x8 b;
                b[0] = f2bf_s(v0.x); b[1] = f2bf_s(v0.y); b[2] = f2bf_s(v0.z); b[3] = f2bf_s(v0.w);
                b[4] = f2bf_s(v1.x); b[5] = f2bf_s(v1.y); b[6] = f2bf_s(v1.z); b[7] = f2bf_s(v1.w);
                #pragma unroll
                for (int ct = 0; ct < 8; ++ct)
                    acc[ct] = __builtin_amdgcn_mfma_f32_16x16x32_bf16(a[ct][kc], b, acc[ct], 0, 0, 0);
            }
            if (n0 + m < N) {
                unsigned int* o = h + (size_t)(n0 + m) * (HID_DIM / 2) + quad * 2;
                #pragma unroll
                for (int ct = 0; ct < 8; ++ct) {
                    uint2 pv;
                    pv.x = pack2(acc[ct][0], acc[ct][1]);
                    pv.y = pack2(acc[ct][2], acc[ct][3]);
                    *(uint2*)(o + ct * 8) = pv;
                }
            }
        }
    } else {
        // ---- fill role ----
        int e = (blockIdx.x - G1B) * 256 + tid;
        if (e < E) {
            int s = src[e], d = dst[e];
            int r = (e >> 8) & (NREP - 1);
            int pos = row_start[d] + cntR[(size_t)r * N + d] + rank[e];
            int2 p;
            p.x = s;
            p.y = __float_as_int(dinv[s] * dinv[d]);
            pack[pos] = p;
        }
    }
}

// ---------------- GEMM2 (MFMA): h2[N,64](bf16) = relu(agg(bf16) + b1) @ W2[128,64] ----
__global__ __launch_bounds__(256) void gemm2_mfma(
        const ushort_t* __restrict__ agg, const float* __restrict__ b1,
        const float* __restrict__ W2, unsigned int* __restrict__ h2,
        int N, int NT, int NW) {
    const int tid  = threadIdx.x;
    const int lane = tid & 63;
    const int m    = lane & 15;
    const int quad = lane >> 4;
    const int gw   = blockIdx.x * 4 + (tid >> 6);

    bf16x8 a[4][4];
    #pragma unroll
    for (int ct = 0; ct < 4; ++ct)
        #pragma unroll
        for (int kc = 0; kc < 4; ++kc)
            #pragma unroll
            for (int j = 0; j < 8; ++j)
                a[ct][kc][j] = f2bf_s(W2[(size_t)(kc * 32 + quad * 8 + j) * OUT_DIM + ct * 16 + m]);

    float4 b1v[8];
    #pragma unroll
    for (int kc = 0; kc < 4; ++kc) {
        b1v[kc * 2]     = *(const float4*)(b1 + kc * 32 + quad * 8);
        b1v[kc * 2 + 1] = *(const float4*)(b1 + kc * 32 + quad * 8 + 4);
    }

    for (int t = gw; t < NT; t += NW) {
        const int n0 = t * 16;
        int node = n0 + m; if (node >= N) node = N - 1;
        const ushort_t* ar = agg + (size_t)node * HID_DIM + quad * 8;
        f32x4 acc[4];
        #pragma unroll
        for (int ct = 0; ct < 4; ++ct) acc[ct] = (f32x4){0.f, 0.f, 0.f, 0.f};
        #pragma unroll
        for (int kc = 0; kc < 4; ++kc) {
            const ushort4_t r0 = *(const ushort4_t*)(ar + kc * 32);
            const ushort4_t r1 = *(const ushort4_t*)(ar + kc * 32 + 4);
            const float4 ba = b1v[kc * 2], bb = b1v[kc * 2 + 1];
            bf16x8 b;
            b[0] = f2bf_s(fmaxf(bf2f(r0.x) + ba.x, 0.f));
            b[1] = f2bf_s(fmaxf(bf2f(r0.y) + ba.y, 0.f));
            b[2] = f2bf_s(fmaxf(bf2f(r0.z) + ba.z, 0.f));
            b[3] = f2bf_s(fmaxf(bf2f(r0.w) + ba.w, 0.f));
            b[4] = f2bf_s(fmaxf(bf2f(r1.x) + bb.x, 0.f));
            b[5] = f2bf_s(fmaxf(bf2f(r1.y) + bb.y, 0.f));
            b[6] = f2bf_s(fmaxf(bf2f(r1.z) + bb.z, 0.f));
            b[7] = f2bf_s(fmaxf(bf2f(r1.w) + bb.w, 0.f));
            #pragma unroll
            for (int ct = 0; ct < 4; ++ct)
                acc[ct] = __builtin_amdgcn_mfma_f32_16x16x32_bf16(a[ct][kc], b, acc[ct], 0, 0, 0);
        }
        if (n0 + m < N) {
            unsigned int* o = h2 + (size_t)(n0 + m) * (OUT_DIM / 2) + quad * 2;
            #pragma unroll
            for (int ct = 0; ct < 4; ++ct) {
                uint2 pv;
                pv.x = pack2(acc[ct][0], acc[ct][1]);
                pv.y = pack2(acc[ct][2], acc[ct][3]);
                *(uint2*)(o + ct * 8) = pv;
            }
        }
    }
}

// ---------------- gather aggregation, bf16 messages, padded packed records ----------
// cntp already padded to x4; pad records {0,0.0f} are no-ops.
template<int D, bool BF16_OUT>
__global__ void gather_bf16(const ushort_t* __restrict__ h, const int2* __restrict__ pack,
                            const int* __restrict__ row_start, const int* __restrict__ cntp,
                            const float* __restrict__ dinv, const float* __restrict__ bias,
                            int N, void* __restrict__ outv) {
    const int TPN = D / 4;
    const int NPB = 256 / TPN;
    const int t = threadIdx.x;
    const int node = blockIdx.x * NPB + t / TPN;
    if (node >= N) return;
    const int f = (t & (TPN - 1)) * 4;
    const float dd = dinv[node];

    const ushort4_t self = *(const ushort4_t*)(h + (size_t)node * D + f);
    const float sn = dd * dd;
    float4 acc;
    acc.x = bf2f(self.x) * sn; acc.y = bf2f(self.y) * sn;
    acc.z = bf2f(self.z) * sn; acc.w = bf2f(self.w) * sn;
    if (bias) {
        const float4 b = *(const float4*)(bias + f);
        acc.x += b.x; acc.y += b.y; acc.z += b.z; acc.w += b.w;
    }

    const int2* pk = pack + row_start[node];       // 16B-aligned (start % 4 == 0)
    const int cpad = cntp[node];
    for (int e = 0; e < cpad; e += 4) {
        const int4 a = *(const int4*)(pk + e);
        const int4 b = *(const int4*)(pk + e + 2);
        {
            const ushort4_t v = *(const ushort4_t*)(h + (size_t)a.x * D + f);
            const float n = __int_as_float(a.y);
            acc.x += bf2f(v.x) * n; acc.y += bf2f(v.y) * n;
            acc.z += bf2f(v.z) * n; acc.w += bf2f(v.w) * n;
        }
        {
            const ushort4_t v = *(const ushort4_t*)(h + (size_t)a.z * D + f);
            const float n = __int_as_float(a.w);
            acc.x += bf2f(v.x) * n; acc.y += bf2f(v.y) * n;
            acc.z += bf2f(v.z) * n; acc.w += bf2f(v.w) * n;
        }
        {
            const ushort4_t v = *(const ushort4_t*)(h + (size_t)b.x * D + f);
            const float n = __int_as_float(b.y);
            acc.x += bf2f(v.x) * n; acc.y += bf2f(v.y) * n;
            acc.z += bf2f(v.z) * n; acc.w += bf2f(v.w) * n;
        }
        {
            const ushort4_t v = *(const ushort4_t*)(h + (size_t)b.z * D + f);
            const float n = __int_as_float(b.w);
            acc.x += bf2f(v.x) * n; acc.y += bf2f(v.y) * n;
            acc.z += bf2f(v.z) * n; acc.w += bf2f(v.w) * n;
        }
    }
    if (BF16_OUT) {
        unsigned int* out = (unsigned int*)outv;
        uint2 pv;
        pv.x = pack2(acc.x, acc.y);
        pv.y = pack2(acc.z, acc.w);
        *(uint2*)(out + ((size_t)node * D + f) / 2) = pv;
    } else {
        float* out = (float*)outv;
        *(float4*)(out + (size_t)node * D + f) = acc;
    }
}

extern "C" void kernel_launch(void* const* d_in, const int* in_sizes, int n_in,
                              void* d_out, int out_size, void* d_ws, size_t ws_size,
                              hipStream_t stream) {
    const float* x   = (const float*)d_in[0];
    const int*   ei  = (const int*)  d_in[1];
    const float* W1  = (const float*)d_in[2];
    const float* b1  = (const float*)d_in[3];
    const float* W2  = (const float*)d_in[4];
    const float* b2  = (const float*)d_in[5];
    float* out = (float*)d_out;

    const int N = in_sizes[0] / IN_DIM;     // 100000
    const int E = in_sizes[1] / 2;          // 1600000
    const int* src = ei;                    // edge_index[0]
    const int* dst = ei + E;                // edge_index[1]

    // workspace (4B units):
    // dinv[N] | cntp[N] | row_start[N] | bsum[1024] | cntR[8N] | align | pack[E+4N] int2
    // | h1[N*64] u32 (bf16, reused as h2) | agg1[N*64] u32 (bf16; rank aliases it)
    const int PACK_CAP = E + 4 * N;
    float* dinv      = (float*)d_ws;
    int*   cntp      = (int*)(dinv + N);
    int*   row_start = cntp + N;
    int*   bsum      = row_start + N;
    int*   cntR      = bsum + 1024;
    size_t off       = (size_t)(3 * N + 1024 + NREP * N);
    off = (off + 3) & ~(size_t)3;           // 16B-align pack
    int2*  pack      = (int2*)((int*)d_ws + off);
    unsigned int* h1 = (unsigned int*)(pack + PACK_CAP);
    unsigned int* agg1 = h1 + (size_t)N * (HID_DIM / 2);
    int*   rank      = (int*)agg1;          // alive only until fused fill
    unsigned int* h2 = h1;                  // reuse after gather128

    const int B = 256;
    const int S = (N + 2047) / 2048;        // node_totals / scan blocks
    const int NT = (N + 15) / 16;           // 16-node MFMA tiles

    // 1) CSR build + dinv
    hipMemsetAsync(cntR, 0, (size_t)NREP * N * sizeof(int), stream);
    hipMemsetAsync(pack, 0, (size_t)PACK_CAP * sizeof(int2), stream);
    count_rank<<<(E + B - 1) / B, B, 0, stream>>>(dst, E, N, cntR, rank);
    node_totals<<<S, 256, 0, stream>>>(cntR, dinv, cntp, bsum, N);
    scan_partials<<<1, 64, 0, stream>>>(bsum, S);
    scan_write<<<S, 256, 0, stream>>>(cntp, bsum, row_start, N);

    // 2) fused: h1 = x @ W1 (MFMA)  +  pack fill
    {
        int fillBlocks = (E + 255) / 256;
        fused_fill_gemm1<<<G1B + fillBlocks, 256, 0, stream>>>(
            src, dst, rank, row_start, cntR, dinv, pack, E,
            x, W1, h1, N, NT);
    }

    // 3) agg1 = gather(h1)  (bf16 out; overwrites rank)
    gather_bf16<HID_DIM, true><<<(N + 7) / 8, 256, 0, stream>>>(
        (const ushort_t*)h1, pack, row_start, cntp, dinv, nullptr, N, (void*)agg1);

    // 4) h2 = relu(agg1 + b1) @ W2  (bf16 out, MFMA)
    gemm2_mfma<<<768, 256, 0, stream>>>(
        (const ushort_t*)agg1, b1, W2, h2, N, NT, 768 * 4);

    // 5) out = b2 + gather(h2)  (f32 out)
    gather_bf16<OUT_DIM, false><<<(N + 15) / 16, 256, 0, stream>>>(
        (const ushort_t*)h2, pack, row_start, cntp, dinv, b2, N, (void*)out);
}

// Round 8
// 354.764 us; speedup vs baseline: 1.0241x; 1.0241x over previous
//
#include <hip/hip_runtime.h>
#include <hip/hip_bf16.h>

#define IN_DIM  128
#define HID_DIM 128
#define OUT_DIM 64
#define NREP    8          // counter replicas (contention /8)

typedef unsigned short ushort_t;
struct ushort4_t { ushort_t x, y, z, w; };
typedef __attribute__((ext_vector_type(8))) short bf16x8;   // 8 bf16 (4 VGPRs)
typedef __attribute__((ext_vector_type(4))) float f32x4;    // MFMA acc

__device__ __forceinline__ float bf2f(ushort_t u) {
    return __uint_as_float(((unsigned int)u) << 16);
}
__device__ __forceinline__ short f2bf_s(float v) {
    __hip_bfloat16 t = __float2bfloat16(v);
    return *(short*)&t;
}
__device__ __forceinline__ unsigned int pack2(float a, float b) {
    return ((unsigned int)(ushort_t)f2bf_s(b) << 16) | (ushort_t)f2bf_s(a);
}

// ---------------- replicated degree count + per-edge rank ----------------
__global__ void count_rank(const int* __restrict__ dst, int E, int N,
                           int* __restrict__ cntR, int* __restrict__ rank) {
    int e = blockIdx.x * blockDim.x + threadIdx.x;
    if (e < E) {
        int r = (e >> 8) & (NREP - 1);
        rank[e] = atomicAdd(&cntR[(size_t)r * N + dst[e]], 1);
    }
}

// ---------------- per-node totals: replica prefix (in place), dinv, padded cnt,
// ---------------- and per-block sums (merged scan_partial) ----------------
__global__ void node_totals(int* __restrict__ cntR, float* __restrict__ dinv,
                            int* __restrict__ cntp, int* __restrict__ bsum, int N) {
    __shared__ int wsum[4];
    const int t = threadIdx.x;
    const int base = blockIdx.x * 2048 + t * 8;
    int ssum = 0;
    #pragma unroll
    for (int i = 0; i < 8; ++i) {
        const int idx = base + i;
        if (idx < N) {
            int b = 0;
            #pragma unroll
            for (int r = 0; r < NREP; ++r) {
                int c = cntR[(size_t)r * N + idx];
                cntR[(size_t)r * N + idx] = b;   // exclusive base for fill
                b += c;
            }
            dinv[idx] = rsqrtf((float)(b + 1));  // +1 self loop
            int p = (b + 7) & ~7;                // pad to 8 records = one 64B line
            cntp[idx] = p;
            ssum += p;
        }
    }
    #pragma unroll
    for (int off = 32; off > 0; off >>= 1) ssum += __shfl_down(ssum, off);
    const int lane = t & 63, w = t >> 6;
    if (lane == 0) wsum[w] = ssum;
    __syncthreads();
    if (t == 0) bsum[blockIdx.x] = wsum[0] + wsum[1] + wsum[2] + wsum[3];
}

__global__ void scan_partials(int* __restrict__ bsum, int S) {
    const int t = threadIdx.x;  // 64 threads, single wave
    int running = 0;
    for (int base = 0; base < S; base += 64) {
        int i = base + t;
        int v = (i < S) ? bsum[i] : 0;
        int incl = v;
        #pragma unroll
        for (int off = 1; off < 64; off <<= 1) {
            int u = __shfl_up(incl, off);
            if (t >= off) incl += u;
        }
        if (i < S) bsum[i] = running + incl - v;   // exclusive
        running += __shfl(incl, 63);
    }
}

__global__ void scan_write(const int* __restrict__ cntp, const int* __restrict__ bsum,
                           int* __restrict__ row_start, int N) {
    __shared__ int wsum[4];
    const int t = threadIdx.x;
    const int base = blockIdx.x * 2048 + t * 8;
    int v[8];
    #pragma unroll
    for (int i = 0; i < 8; ++i) v[i] = (base + i < N) ? cntp[base + i] : 0;
    int s = v[0] + v[1] + v[2] + v[3] + v[4] + v[5] + v[6] + v[7];
    const int lane = t & 63, w = t >> 6;
    int incl = s;
    #pragma unroll
    for (int off = 1; off < 64; off <<= 1) {
        int u = __shfl_up(incl, off);
        if (lane >= off) incl += u;
    }
    if (lane == 63) wsum[w] = incl;
    __syncthreads();
    int woff = 0;
    for (int i = 0; i < w; ++i) woff += wsum[i];
    int run = bsum[blockIdx.x] + woff + (incl - s);
    #pragma unroll
    for (int i = 0; i < 8; ++i) {
        if (base + i < N) row_start[base + i] = run;
        run += v[i];
    }
}

// ---------------- fill packed CSR records {src, norm} (no atomics) ----------------
// pack[] pre-zeroed; padded slots stay {0, 0.0f} -> contribute nothing.
__global__ void fill_pack(const int* __restrict__ src, const int* __restrict__ dst,
                          const int* __restrict__ rank, const int* __restrict__ row_start,
                          const int* __restrict__ cntR, const float* __restrict__ dinv,
                          int E, int N, int2* __restrict__ pack) {
    int e = blockIdx.x * blockDim.x + threadIdx.x;
    if (e < E) {
        int s = src[e], d = dst[e];
        int r = (e >> 8) & (NREP - 1);
        int pos = row_start[d] + cntR[(size_t)r * N + d] + rank[e];
        int2 p;
        p.x = s;
        p.y = __float_as_int(dinv[s] * dinv[d]);
        pack[pos] = p;
    }
}

// ---------------- GEMM1 (MFMA): h1[N,128](bf16) = x[N,128] @ W1[128,128] ----------------
// D = W1^T·x^T per 16-node tile; 4 waves/block, persistent grid-stride.
__global__ __launch_bounds__(256, 2) void gemm1_mfma(
        const float* __restrict__ x, const float* __restrict__ W,
        unsigned int* __restrict__ h, int N, int NT, int NW) {
    const int tid  = threadIdx.x;
    const int lane = tid & 63;
    const int m    = lane & 15;
    const int quad = lane >> 4;
    const int gw   = blockIdx.x * 4 + (tid >> 6);

    bf16x8 a[8][4];                         // 8 col-tiles x 4 k-chunks
    #pragma unroll
    for (int ct = 0; ct < 8; ++ct)
        #pragma unroll
        for (int kc = 0; kc < 4; ++kc)
            #pragma unroll
            for (int j = 0; j < 8; ++j)
                a[ct][kc][j] = f2bf_s(W[(size_t)(kc * 32 + quad * 8 + j) * HID_DIM + ct * 16 + m]);

    for (int t = gw; t < NT; t += NW) {
        const int n0 = t * 16;
        int node = n0 + m; if (node >= N) node = N - 1;
        const float* xr = x + (size_t)node * IN_DIM + quad * 8;
        f32x4 acc[8];
        #pragma unroll
        for (int ct = 0; ct < 8; ++ct) acc[ct] = (f32x4){0.f, 0.f, 0.f, 0.f};
        #pragma unroll
        for (int kc = 0; kc < 4; ++kc) {
            const float4 v0 = *(const float4*)(xr + kc * 32);
            const float4 v1 = *(const float4*)(xr + kc * 32 + 4);
            bf16x8 b;
            b[0] = f2bf_s(v0.x); b[1] = f2bf_s(v0.y); b[2] = f2bf_s(v0.z); b[3] = f2bf_s(v0.w);
            b[4] = f2bf_s(v1.x); b[5] = f2bf_s(v1.y); b[6] = f2bf_s(v1.z); b[7] = f2bf_s(v1.w);
            #pragma unroll
            for (int ct = 0; ct < 8; ++ct)
                acc[ct] = __builtin_amdgcn_mfma_f32_16x16x32_bf16(a[ct][kc], b, acc[ct], 0, 0, 0);
        }
        if (n0 + m < N) {
            unsigned int* o = h + (size_t)(n0 + m) * (HID_DIM / 2) + quad * 2;
            #pragma unroll
            for (int ct = 0; ct < 8; ++ct) {
                uint2 pv;
                pv.x = pack2(acc[ct][0], acc[ct][1]);
                pv.y = pack2(acc[ct][2], acc[ct][3]);
                *(uint2*)(o + ct * 8) = pv;
            }
        }
    }
}

// ---------------- GEMM2 (MFMA): h2[N,64](bf16) = relu(agg(bf16) + b1) @ W2[128,64] ----
__global__ __launch_bounds__(256) void gemm2_mfma(
        const ushort_t* __restrict__ agg, const float* __restrict__ b1,
        const float* __restrict__ W2, unsigned int* __restrict__ h2,
        int N, int NT, int NW) {
    const int tid  = threadIdx.x;
    const int lane = tid & 63;
    const int m    = lane & 15;
    const int quad = lane >> 4;
    const int gw   = blockIdx.x * 4 + (tid >> 6);

    bf16x8 a[4][4];
    #pragma unroll
    for (int ct = 0; ct < 4; ++ct)
        #pragma unroll
        for (int kc = 0; kc < 4; ++kc)
            #pragma unroll
            for (int j = 0; j < 8; ++j)
                a[ct][kc][j] = f2bf_s(W2[(size_t)(kc * 32 + quad * 8 + j) * OUT_DIM + ct * 16 + m]);

    float4 b1v[8];
    #pragma unroll
    for (int kc = 0; kc < 4; ++kc) {
        b1v[kc * 2]     = *(const float4*)(b1 + kc * 32 + quad * 8);
        b1v[kc * 2 + 1] = *(const float4*)(b1 + kc * 32 + quad * 8 + 4);
    }

    for (int t = gw; t < NT; t += NW) {
        const int n0 = t * 16;
        int node = n0 + m; if (node >= N) node = N - 1;
        const ushort_t* ar = agg + (size_t)node * HID_DIM + quad * 8;
        f32x4 acc[4];
        #pragma unroll
        for (int ct = 0; ct < 4; ++ct) acc[ct] = (f32x4){0.f, 0.f, 0.f, 0.f};
        #pragma unroll
        for (int kc = 0; kc < 4; ++kc) {
            const ushort4_t r0 = *(const ushort4_t*)(ar + kc * 32);
            const ushort4_t r1 = *(const ushort4_t*)(ar + kc * 32 + 4);
            const float4 ba = b1v[kc * 2], bb = b1v[kc * 2 + 1];
            bf16x8 b;
            b[0] = f2bf_s(fmaxf(bf2f(r0.x) + ba.x, 0.f));
            b[1] = f2bf_s(fmaxf(bf2f(r0.y) + ba.y, 0.f));
            b[2] = f2bf_s(fmaxf(bf2f(r0.z) + ba.z, 0.f));
            b[3] = f2bf_s(fmaxf(bf2f(r0.w) + ba.w, 0.f));
            b[4] = f2bf_s(fmaxf(bf2f(r1.x) + bb.x, 0.f));
            b[5] = f2bf_s(fmaxf(bf2f(r1.y) + bb.y, 0.f));
            b[6] = f2bf_s(fmaxf(bf2f(r1.z) + bb.z, 0.f));
            b[7] = f2bf_s(fmaxf(bf2f(r1.w) + bb.w, 0.f));
            #pragma unroll
            for (int ct = 0; ct < 4; ++ct)
                acc[ct] = __builtin_amdgcn_mfma_f32_16x16x32_bf16(a[ct][kc], b, acc[ct], 0, 0, 0);
        }
        if (n0 + m < N) {
            unsigned int* o = h2 + (size_t)(n0 + m) * (OUT_DIM / 2) + quad * 2;
            #pragma unroll
            for (int ct = 0; ct < 4; ++ct) {
                uint2 pv;
                pv.x = pack2(acc[ct][0], acc[ct][1]);
                pv.y = pack2(acc[ct][2], acc[ct][3]);
                *(uint2*)(o + ct * 8) = pv;
            }
        }
    }
}

// ---------------- gather aggregation, bf16 messages, 8-record (64B) padded rows ----
// Pad records {0,0.0f}: row-0 reads are L1-hot, norm=0 -> no-op.
template<int D, bool BF16_OUT>
__global__ void gather_bf16(const ushort_t* __restrict__ h, const int2* __restrict__ pack,
                            const int* __restrict__ row_start, const int* __restrict__ cntp,
                            const float* __restrict__ dinv, const float* __restrict__ bias,
                            int N, void* __restrict__ outv) {
    const int TPN = D / 4;
    const int NPB = 256 / TPN;
    const int t = threadIdx.x;
    const int node = blockIdx.x * NPB + t / TPN;
    if (node >= N) return;
    const int f = (t & (TPN - 1)) * 4;
    const float dd = dinv[node];

    const ushort4_t self = *(const ushort4_t*)(h + (size_t)node * D + f);
    const float sn = dd * dd;
    float4 acc;
    acc.x = bf2f(self.x) * sn; acc.y = bf2f(self.y) * sn;
    acc.z = bf2f(self.z) * sn; acc.w = bf2f(self.w) * sn;
    if (bias) {
        const float4 b = *(const float4*)(bias + f);
        acc.x += b.x; acc.y += b.y; acc.z += b.z; acc.w += b.w;
    }

    const int2* pk = pack + row_start[node];       // 64B-aligned (start % 8 == 0)
    const int cpad = cntp[node];
    for (int e = 0; e < cpad; e += 8) {
        const int4 p0 = *(const int4*)(pk + e);
        const int4 p1 = *(const int4*)(pk + e + 2);
        const int4 p2 = *(const int4*)(pk + e + 4);
        const int4 p3 = *(const int4*)(pk + e + 6);
        int   si[8];
        float ni[8];
        si[0] = p0.x; ni[0] = __int_as_float(p0.y);
        si[1] = p0.z; ni[1] = __int_as_float(p0.w);
        si[2] = p1.x; ni[2] = __int_as_float(p1.y);
        si[3] = p1.z; ni[3] = __int_as_float(p1.w);
        si[4] = p2.x; ni[4] = __int_as_float(p2.y);
        si[5] = p2.z; ni[5] = __int_as_float(p2.w);
        si[6] = p3.x; ni[6] = __int_as_float(p3.y);
        si[7] = p3.z; ni[7] = __int_as_float(p3.w);
        ushort4_t v[8];
        #pragma unroll
        for (int i = 0; i < 8; ++i)
            v[i] = *(const ushort4_t*)(h + (size_t)si[i] * D + f);
        #pragma unroll
        for (int i = 0; i < 8; ++i) {
            acc.x += bf2f(v[i].x) * ni[i]; acc.y += bf2f(v[i].y) * ni[i];
            acc.z += bf2f(v[i].z) * ni[i]; acc.w += bf2f(v[i].w) * ni[i];
        }
    }
    if (BF16_OUT) {
        unsigned int* out = (unsigned int*)outv;
        uint2 pv;
        pv.x = pack2(acc.x, acc.y);
        pv.y = pack2(acc.z, acc.w);
        *(uint2*)(out + ((size_t)node * D + f) / 2) = pv;
    } else {
        float* out = (float*)outv;
        *(float4*)(out + (size_t)node * D + f) = acc;
    }
}

extern "C" void kernel_launch(void* const* d_in, const int* in_sizes, int n_in,
                              void* d_out, int out_size, void* d_ws, size_t ws_size,
                              hipStream_t stream) {
    const float* x   = (const float*)d_in[0];
    const int*   ei  = (const int*)  d_in[1];
    const float* W1  = (const float*)d_in[2];
    const float* b1  = (const float*)d_in[3];
    const float* W2  = (const float*)d_in[4];
    const float* b2  = (const float*)d_in[5];
    float* out = (float*)d_out;

    const int N = in_sizes[0] / IN_DIM;     // 100000
    const int E = in_sizes[1] / 2;          // 1600000
    const int* src = ei;                    // edge_index[0]
    const int* dst = ei + E;                // edge_index[1]

    // workspace (4B units):
    // dinv[N] | cntp[N] | row_start[N] | bsum[1024] | cntR[8N] | align | pack[E+8N] int2
    // | h1[N*64] u32 (bf16, reused as h2) | agg1[N*64] u32 (bf16; rank aliases it)
    const int PACK_CAP = E + 8 * N;
    float* dinv      = (float*)d_ws;
    int*   cntp      = (int*)(dinv + N);
    int*   row_start = cntp + N;
    int*   bsum      = row_start + N;
    int*   cntR      = bsum + 1024;
    size_t off       = (size_t)(3 * N + 1024 + NREP * N);
    off = (off + 3) & ~(size_t)3;           // 16B-align pack
    int2*  pack      = (int2*)((int*)d_ws + off);
    unsigned int* h1 = (unsigned int*)(pack + PACK_CAP);
    unsigned int* agg1 = h1 + (size_t)N * (HID_DIM / 2);
    int*   rank      = (int*)agg1;          // alive only until fill_pack
    unsigned int* h2 = h1;                  // reuse after gather128

    const int B = 256;
    const int S = (N + 2047) / 2048;        // node_totals / scan blocks
    const int NT = (N + 15) / 16;           // 16-node MFMA tiles

    // 1) CSR build + dinv
    hipMemsetAsync(cntR, 0, (size_t)NREP * N * sizeof(int), stream);
    hipMemsetAsync(pack, 0, (size_t)PACK_CAP * sizeof(int2), stream);
    count_rank<<<(E + B - 1) / B, B, 0, stream>>>(dst, E, N, cntR, rank);
    node_totals<<<S, 256, 0, stream>>>(cntR, dinv, cntp, bsum, N);
    scan_partials<<<1, 64, 0, stream>>>(bsum, S);
    scan_write<<<S, 256, 0, stream>>>(cntp, bsum, row_start, N);
    fill_pack<<<(E + B - 1) / B, B, 0, stream>>>(
        src, dst, rank, row_start, cntR, dinv, E, N, pack);

    // 2) h1 = x @ W1  (bf16 out, MFMA)
    gemm1_mfma<<<512, 256, 0, stream>>>(x, W1, h1, N, NT, 512 * 4);

    // 3) agg1 = gather(h1)  (bf16 out; overwrites rank)
    gather_bf16<HID_DIM, true><<<(N + 7) / 8, 256, 0, stream>>>(
        (const ushort_t*)h1, pack, row_start, cntp, dinv, nullptr, N, (void*)agg1);

    // 4) h2 = relu(agg1 + b1) @ W2  (bf16 out, MFMA)
    gemm2_mfma<<<768, 256, 0, stream>>>(
        (const ushort_t*)agg1, b1, W2, h2, N, NT, 768 * 4);

    // 5) out = b2 + gather(h2)  (f32 out)
    gather_bf16<OUT_DIM, false><<<(N + 15) / 16, 256, 0, stream>>>(
        (const ushort_t*)h2, pack, row_start, cntp, dinv, b2, N, (void*)out);
}

// Round 9
// 349.399 us; speedup vs baseline: 1.0399x; 1.0154x over previous
//
#include <hip/hip_runtime.h>
#include <hip/hip_bf16.h>

#define IN_DIM  128
#define HID_DIM 128
#define OUT_DIM 64
#define NREP    8          // counter replicas = XCD count (XCD-local atomics)

typedef unsigned short ushort_t;
struct ushort4_t { ushort_t x, y, z, w; };
typedef __attribute__((ext_vector_type(8))) short bf16x8;   // 8 bf16 (4 VGPRs)
typedef __attribute__((ext_vector_type(4))) float f32x4;    // MFMA acc

__device__ __forceinline__ float bf2f(ushort_t u) {
    return __uint_as_float(((unsigned int)u) << 16);
}
__device__ __forceinline__ short f2bf_s(float v) {
    __hip_bfloat16 t = __float2bfloat16(v);
    return *(short*)&t;
}
__device__ __forceinline__ unsigned int pack2(float a, float b) {
    return ((unsigned int)(ushort_t)f2bf_s(b) << 16) | (ushort_t)f2bf_s(a);
}
// two bf16 packed in one u32 -> two f32 (shift for lo, AND for hi)
__device__ __forceinline__ void bf2x(unsigned int u, float& lo, float& hi) {
    lo = __uint_as_float(u << 16);
    hi = __uint_as_float(u & 0xffff0000u);
}
// XCD id (0..7 on MI355X); masked so any HW value stays in range.
__device__ __forceinline__ int xcc_id() {
    return __builtin_amdgcn_s_getreg((3 << 11) | (0 << 6) | 20) & (NREP - 1);
}

// ---------------- XCD-local replicated degree count + per-edge rank ----------------
// rank[e] packs {replica:4, rank:28} so fill_pack can recover the replica.
__global__ void count_rank(const int* __restrict__ dst, int E, int N,
                           int* __restrict__ cntR, int* __restrict__ rank) {
    int e = blockIdx.x * blockDim.x + threadIdx.x;
    if (e < E) {
        int r = xcc_id();                    // wave-uniform, XCD-local counters
        int rk = atomicAdd(&cntR[(size_t)r * N + dst[e]], 1);
        rank[e] = (r << 28) | rk;
    }
}

// ---------------- per-node totals: replica prefix (in place), dinv, padded cnt,
// ---------------- and per-block sums (merged scan_partial) ----------------
__global__ void node_totals(int* __restrict__ cntR, float* __restrict__ dinv,
                            int* __restrict__ cntp, int* __restrict__ bsum, int N) {
    __shared__ int wsum[4];
    const int t = threadIdx.x;
    const int base = blockIdx.x * 2048 + t * 8;
    int ssum = 0;
    #pragma unroll
    for (int i = 0; i < 8; ++i) {
        const int idx = base + i;
        if (idx < N) {
            int b = 0;
            #pragma unroll
            for (int r = 0; r < NREP; ++r) {
                int c = cntR[(size_t)r * N + idx];
                cntR[(size_t)r * N + idx] = b;   // exclusive base for fill
                b += c;
            }
            dinv[idx] = rsqrtf((float)(b + 1));  // +1 self loop
            int p = (b + 7) & ~7;                // pad to 8 records = one 64B line
            cntp[idx] = p;
            ssum += p;
        }
    }
    #pragma unroll
    for (int off = 32; off > 0; off >>= 1) ssum += __shfl_down(ssum, off);
    const int lane = t & 63, w = t >> 6;
    if (lane == 0) wsum[w] = ssum;
    __syncthreads();
    if (t == 0) bsum[blockIdx.x] = wsum[0] + wsum[1] + wsum[2] + wsum[3];
}

__global__ void scan_partials(int* __restrict__ bsum, int S) {
    const int t = threadIdx.x;  // 64 threads, single wave
    int running = 0;
    for (int base = 0; base < S; base += 64) {
        int i = base + t;
        int v = (i < S) ? bsum[i] : 0;
        int incl = v;
        #pragma unroll
        for (int off = 1; off < 64; off <<= 1) {
            int u = __shfl_up(incl, off);
            if (t >= off) incl += u;
        }
        if (i < S) bsum[i] = running + incl - v;   // exclusive
        running += __shfl(incl, 63);
    }
}

__global__ void scan_write(const int* __restrict__ cntp, const int* __restrict__ bsum,
                           int* __restrict__ row_start, int N) {
    __shared__ int wsum[4];
    const int t = threadIdx.x;
    const int base = blockIdx.x * 2048 + t * 8;
    int v[8];
    #pragma unroll
    for (int i = 0; i < 8; ++i) v[i] = (base + i < N) ? cntp[base + i] : 0;
    int s = v[0] + v[1] + v[2] + v[3] + v[4] + v[5] + v[6] + v[7];
    const int lane = t & 63, w = t >> 6;
    int incl = s;
    #pragma unroll
    for (int off = 1; off < 64; off <<= 1) {
        int u = __shfl_up(incl, off);
        if (lane >= off) incl += u;
    }
    if (lane == 63) wsum[w] = incl;
    __syncthreads();
    int woff = 0;
    for (int i = 0; i < w; ++i) woff += wsum[i];
    int run = bsum[blockIdx.x] + woff + (incl - s);
    #pragma unroll
    for (int i = 0; i < 8; ++i) {
        if (base + i < N) row_start[base + i] = run;
        run += v[i];
    }
}

// ---------------- fill packed CSR records {src, norm} (no atomics) ----------------
// pack[] pre-zeroed; padded slots stay {0, 0.0f} -> contribute nothing.
__global__ void fill_pack(const int* __restrict__ src, const int* __restrict__ dst,
                          const int* __restrict__ rank, const int* __restrict__ row_start,
                          const int* __restrict__ cntR, const float* __restrict__ dinv,
                          int E, int N, int2* __restrict__ pack) {
    int e = blockIdx.x * blockDim.x + threadIdx.x;
    if (e < E) {
        int s = src[e], d = dst[e];
        int rr = rank[e];
        int r  = (unsigned int)rr >> 28;
        int rk = rr & 0x0FFFFFFF;
        int pos = row_start[d] + cntR[(size_t)r * N + d] + rk;
        int2 p;
        p.x = s;
        p.y = __float_as_int(dinv[s] * dinv[d]);
        pack[pos] = p;
    }
}

// ---------------- GEMM1 (MFMA): h1[N,128](bf16) = x[N,128] @ W1[128,128] ----------------
// D = W1^T·x^T per 16-node tile; 4 waves/block, persistent grid-stride.
__global__ __launch_bounds__(256, 2) void gemm1_mfma(
        const float* __restrict__ x, const float* __restrict__ W,
        unsigned int* __restrict__ h, int N, int NT, int NW) {
    const int tid  = threadIdx.x;
    const int lane = tid & 63;
    const int m    = lane & 15;
    const int quad = lane >> 4;
    const int gw   = blockIdx.x * 4 + (tid >> 6);

    bf16x8 a[8][4];                         // 8 col-tiles x 4 k-chunks
    #pragma unroll
    for (int ct = 0; ct < 8; ++ct)
        #pragma unroll
        for (int kc = 0; kc < 4; ++kc)
            #pragma unroll
            for (int j = 0; j < 8; ++j)
                a[ct][kc][j] = f2bf_s(W[(size_t)(kc * 32 + quad * 8 + j) * HID_DIM + ct * 16 + m]);

    for (int t = gw; t < NT; t += NW) {
        const int n0 = t * 16;
        int node = n0 + m; if (node >= N) node = N - 1;
        const float* xr = x + (size_t)node * IN_DIM + quad * 8;
        f32x4 acc[8];
        #pragma unroll
        for (int ct = 0; ct < 8; ++ct) acc[ct] = (f32x4){0.f, 0.f, 0.f, 0.f};
        #pragma unroll
        for (int kc = 0; kc < 4; ++kc) {
            const float4 v0 = *(const float4*)(xr + kc * 32);
            const float4 v1 = *(const float4*)(xr + kc * 32 + 4);
            bf16x8 b;
            b[0] = f2bf_s(v0.x); b[1] = f2bf_s(v0.y); b[2] = f2bf_s(v0.z); b[3] = f2bf_s(v0.w);
            b[4] = f2bf_s(v1.x); b[5] = f2bf_s(v1.y); b[6] = f2bf_s(v1.z); b[7] = f2bf_s(v1.w);
            #pragma unroll
            for (int ct = 0; ct < 8; ++ct)
                acc[ct] = __builtin_amdgcn_mfma_f32_16x16x32_bf16(a[ct][kc], b, acc[ct], 0, 0, 0);
        }
        if (n0 + m < N) {
            unsigned int* o = h + (size_t)(n0 + m) * (HID_DIM / 2) + quad * 2;
            #pragma unroll
            for (int ct = 0; ct < 8; ++ct) {
                uint2 pv;
                pv.x = pack2(acc[ct][0], acc[ct][1]);
                pv.y = pack2(acc[ct][2], acc[ct][3]);
                *(uint2*)(o + ct * 8) = pv;
            }
        }
    }
}

// ---------------- GEMM2 (MFMA): h2[N,64](bf16) = relu(agg(bf16) + b1) @ W2[128,64] ----
__global__ __launch_bounds__(256) void gemm2_mfma(
        const ushort_t* __restrict__ agg, const float* __restrict__ b1,
        const float* __restrict__ W2, unsigned int* __restrict__ h2,
        int N, int NT, int NW) {
    const int tid  = threadIdx.x;
    const int lane = tid & 63;
    const int m    = lane & 15;
    const int quad = lane >> 4;
    const int gw   = blockIdx.x * 4 + (tid >> 6);

    bf16x8 a[4][4];
    #pragma unroll
    for (int ct = 0; ct < 4; ++ct)
        #pragma unroll
        for (int kc = 0; kc < 4; ++kc)
            #pragma unroll
            for (int j = 0; j < 8; ++j)
                a[ct][kc][j] = f2bf_s(W2[(size_t)(kc * 32 + quad * 8 + j) * OUT_DIM + ct * 16 + m]);

    float4 b1v[8];
    #pragma unroll
    for (int kc = 0; kc < 4; ++kc) {
        b1v[kc * 2]     = *(const float4*)(b1 + kc * 32 + quad * 8);
        b1v[kc * 2 + 1] = *(const float4*)(b1 + kc * 32 + quad * 8 + 4);
    }

    for (int t = gw; t < NT; t += NW) {
        const int n0 = t * 16;
        int node = n0 + m; if (node >= N) node = N - 1;
        const ushort_t* ar = agg + (size_t)node * HID_DIM + quad * 8;
        f32x4 acc[4];
        #pragma unroll
        for (int ct = 0; ct < 4; ++ct) acc[ct] = (f32x4){0.f, 0.f, 0.f, 0.f};
        #pragma unroll
        for (int kc = 0; kc < 4; ++kc) {
            const ushort4_t r0 = *(const ushort4_t*)(ar + kc * 32);
            const ushort4_t r1 = *(const ushort4_t*)(ar + kc * 32 + 4);
            const float4 ba = b1v[kc * 2], bb = b1v[kc * 2 + 1];
            bf16x8 b;
            b[0] = f2bf_s(fmaxf(bf2f(r0.x) + ba.x, 0.f));
            b[1] = f2bf_s(fmaxf(bf2f(r0.y) + ba.y, 0.f));
            b[2] = f2bf_s(fmaxf(bf2f(r0.z) + ba.z, 0.f));
            b[3] = f2bf_s(fmaxf(bf2f(r0.w) + ba.w, 0.f));
            b[4] = f2bf_s(fmaxf(bf2f(r1.x) + bb.x, 0.f));
            b[5] = f2bf_s(fmaxf(bf2f(r1.y) + bb.y, 0.f));
            b[6] = f2bf_s(fmaxf(bf2f(r1.z) + bb.z, 0.f));
            b[7] = f2bf_s(fmaxf(bf2f(r1.w) + bb.w, 0.f));
            #pragma unroll
            for (int ct = 0; ct < 4; ++ct)
                acc[ct] = __builtin_amdgcn_mfma_f32_16x16x32_bf16(a[ct][kc], b, acc[ct], 0, 0, 0);
        }
        if (n0 + m < N) {
            unsigned int* o = h2 + (size_t)(n0 + m) * (OUT_DIM / 2) + quad * 2;
            #pragma unroll
            for (int ct = 0; ct < 4; ++ct) {
                uint2 pv;
                pv.x = pack2(acc[ct][0], acc[ct][1]);
                pv.y = pack2(acc[ct][2], acc[ct][3]);
                *(uint2*)(o + ct * 8) = pv;
            }
        }
    }
}

// ---------------- gather aggregation, bf16 messages, 16B/lane, 64B padded rows ----
// TPN = D/8 lanes per node, each loads uint4 (8 bf16). Pad records {0,0} are no-ops.
template<int D, bool BF16_OUT>
__global__ void gather_bf16(const ushort_t* __restrict__ h, const int2* __restrict__ pack,
                            const int* __restrict__ row_start, const int* __restrict__ cntp,
                            const float* __restrict__ dinv, const float* __restrict__ bias,
                            int N, void* __restrict__ outv) {
    const int TPN = D / 8;
    const int NPB = 256 / TPN;
    const int t = threadIdx.x;
    const int node = blockIdx.x * NPB + t / TPN;
    if (node >= N) return;
    const int f = (t & (TPN - 1)) * 8;
    const float dd = dinv[node];

    float acc[8];
    {
        const uint4 su = *(const uint4*)(h + (size_t)node * D + f);
        const float sn = dd * dd;
        float l, hi2;
        bf2x(su.x, l, hi2); acc[0] = l * sn; acc[1] = hi2 * sn;
        bf2x(su.y, l, hi2); acc[2] = l * sn; acc[3] = hi2 * sn;
        bf2x(su.z, l, hi2); acc[4] = l * sn; acc[5] = hi2 * sn;
        bf2x(su.w, l, hi2); acc[6] = l * sn; acc[7] = hi2 * sn;
    }
    if (bias) {
        const float4 b0 = *(const float4*)(bias + f);
        const float4 b1 = *(const float4*)(bias + f + 4);
        acc[0] += b0.x; acc[1] += b0.y; acc[2] += b0.z; acc[3] += b0.w;
        acc[4] += b1.x; acc[5] += b1.y; acc[6] += b1.z; acc[7] += b1.w;
    }

    const int2* pk = pack + row_start[node];       // 64B-aligned (start % 8 == 0)
    const int cpad = cntp[node];
    for (int e = 0; e < cpad; e += 8) {
        const int4 p0 = *(const int4*)(pk + e);
        const int4 p1 = *(const int4*)(pk + e + 2);
        const int4 p2 = *(const int4*)(pk + e + 4);
        const int4 p3 = *(const int4*)(pk + e + 6);
        int   si[8];
        float ni[8];
        si[0] = p0.x; ni[0] = __int_as_float(p0.y);
        si[1] = p0.z; ni[1] = __int_as_float(p0.w);
        si[2] = p1.x; ni[2] = __int_as_float(p1.y);
        si[3] = p1.z; ni[3] = __int_as_float(p1.w);
        si[4] = p2.x; ni[4] = __int_as_float(p2.y);
        si[5] = p2.z; ni[5] = __int_as_float(p2.w);
        si[6] = p3.x; ni[6] = __int_as_float(p3.y);
        si[7] = p3.z; ni[7] = __int_as_float(p3.w);
        uint4 v[8];
        #pragma unroll
        for (int i = 0; i < 8; ++i)
            v[i] = *(const uint4*)(h + (size_t)si[i] * D + f);
        #pragma unroll
        for (int i = 0; i < 8; ++i) {
            float l, hi2;
            bf2x(v[i].x, l, hi2); acc[0] += l * ni[i]; acc[1] += hi2 * ni[i];
            bf2x(v[i].y, l, hi2); acc[2] += l * ni[i]; acc[3] += hi2 * ni[i];
            bf2x(v[i].z, l, hi2); acc[4] += l * ni[i]; acc[5] += hi2 * ni[i];
            bf2x(v[i].w, l, hi2); acc[6] += l * ni[i]; acc[7] += hi2 * ni[i];
        }
    }
    if (BF16_OUT) {
        unsigned int* out = (unsigned int*)outv;
        uint4 pv;
        pv.x = pack2(acc[0], acc[1]);
        pv.y = pack2(acc[2], acc[3]);
        pv.z = pack2(acc[4], acc[5]);
        pv.w = pack2(acc[6], acc[7]);
        *(uint4*)(out + ((size_t)node * D + f) / 2) = pv;
    } else {
        float* out = (float*)outv;
        float4 o0 = {acc[0], acc[1], acc[2], acc[3]};
        float4 o1 = {acc[4], acc[5], acc[6], acc[7]};
        *(float4*)(out + (size_t)node * D + f)     = o0;
        *(float4*)(out + (size_t)node * D + f + 4) = o1;
    }
}

extern "C" void kernel_launch(void* const* d_in, const int* in_sizes, int n_in,
                              void* d_out, int out_size, void* d_ws, size_t ws_size,
                              hipStream_t stream) {
    const float* x   = (const float*)d_in[0];
    const int*   ei  = (const int*)  d_in[1];
    const float* W1  = (const float*)d_in[2];
    const float* b1  = (const float*)d_in[3];
    const float* W2  = (const float*)d_in[4];
    const float* b2  = (const float*)d_in[5];
    float* out = (float*)d_out;

    const int N = in_sizes[0] / IN_DIM;     // 100000
    const int E = in_sizes[1] / 2;          // 1600000
    const int* src = ei;                    // edge_index[0]
    const int* dst = ei + E;                // edge_index[1]

    // workspace (4B units):
    // dinv[N] | cntp[N] | row_start[N] | bsum[1024] | cntR[8N] | align | pack[E+8N] int2
    // | h1[N*64] u32 (bf16, reused as h2) | agg1[N*64] u32 (bf16; rank aliases it)
    const int PACK_CAP = E + 8 * N;
    float* dinv      = (float*)d_ws;
    int*   cntp      = (int*)(dinv + N);
    int*   row_start = cntp + N;
    int*   bsum      = row_start + N;
    int*   cntR      = bsum + 1024;
    size_t off       = (size_t)(3 * N + 1024 + NREP * N);
    off = (off + 3) & ~(size_t)3;           // 16B-align pack
    int2*  pack      = (int2*)((int*)d_ws + off);
    unsigned int* h1 = (unsigned int*)(pack + PACK_CAP);
    unsigned int* agg1 = h1 + (size_t)N * (HID_DIM / 2);
    int*   rank      = (int*)agg1;          // alive only until fill_pack
    unsigned int* h2 = h1;                  // reuse after gather128

    const int B = 256;
    const int S = (N + 2047) / 2048;        // node_totals / scan blocks
    const int NT = (N + 15) / 16;           // 16-node MFMA tiles

    // 1) CSR build + dinv
    hipMemsetAsync(cntR, 0, (size_t)NREP * N * sizeof(int), stream);
    hipMemsetAsync(pack, 0, (size_t)PACK_CAP * sizeof(int2), stream);
    count_rank<<<(E + B - 1) / B, B, 0, stream>>>(dst, E, N, cntR, rank);
    node_totals<<<S, 256, 0, stream>>>(cntR, dinv, cntp, bsum, N);
    scan_partials<<<1, 64, 0, stream>>>(bsum, S);
    scan_write<<<S, 256, 0, stream>>>(cntp, bsum, row_start, N);
    fill_pack<<<(E + B - 1) / B, B, 0, stream>>>(
        src, dst, rank, row_start, cntR, dinv, E, N, pack);

    // 2) h1 = x @ W1  (bf16 out, MFMA)
    gemm1_mfma<<<512, 256, 0, stream>>>(x, W1, h1, N, NT, 512 * 4);

    // 3) agg1 = gather(h1)  (bf16 out; overwrites rank)
    gather_bf16<HID_DIM, true><<<(N + 15) / 16, 256, 0, stream>>>(
        (const ushort_t*)h1, pack, row_start, cntp, dinv, nullptr, N, (void*)agg1);

    // 4) h2 = relu(agg1 + b1) @ W2  (bf16 out, MFMA)
    gemm2_mfma<<<768, 256, 0, stream>>>(
        (const ushort_t*)agg1, b1, W2, h2, N, NT, 768 * 4);

    // 5) out = b2 + gather(h2)  (f32 out)
    gather_bf16<OUT_DIM, false><<<(N + 31) / 32, 256, 0, stream>>>(
        (const ushort_t*)h2, pack, row_start, cntp, dinv, b2, N, (void*)out);
}